// Round 1
// baseline (771.991 us; speedup 1.0000x reference)
//
#include <hip/hip_runtime.h>

// Volume rotate + trilinear resample + projection along axis 2.
// Each thread owns one output pixel (b,i,j) and marches the ray
// p(k) = gi*R[:,0] + gj*R[:,1] + gk*R[:,2], k = 0..255.

#define NN 256

__global__ __launch_bounds__(256) void rotproj_kernel(
    const float* __restrict__ vol,
    const float* __restrict__ quats,
    float* __restrict__ out)
{
    const int b = blockIdx.z;
    const int i = blockIdx.y * 16 + threadIdx.y;
    const int j = blockIdx.x * 16 + threadIdx.x;

    // --- quaternion -> rotation matrix (match reference numerics) ---
    const float q0 = quats[b * 4 + 0];
    const float q1 = quats[b * 4 + 1];
    const float q2 = quats[b * 4 + 2];
    const float q3 = quats[b * 4 + 3];
    const float nrm = sqrtf(q0 * q0 + q1 * q1 + q2 * q2 + q3 * q3);
    const float qw = q0 / nrm, qx = q1 / nrm, qy = q2 / nrm, qz = q3 / nrm;

    const float r00 = 1.0f - 2.0f * (qy * qy + qz * qz);
    const float r01 = 2.0f * (qx * qy - qz * qw);
    const float r02 = 2.0f * (qx * qz + qy * qw);
    const float r10 = 2.0f * (qx * qy + qz * qw);
    const float r11 = 1.0f - 2.0f * (qx * qx + qz * qz);
    const float r12 = 2.0f * (qy * qz - qx * qw);
    const float r20 = 2.0f * (qx * qz - qy * qw);
    const float r21 = 2.0f * (qy * qz + qx * qw);
    const float r22 = 1.0f - 2.0f * (qx * qx + qy * qy);

    const float gi = (float)i - 128.0f;
    const float gj = (float)j - 128.0f;

    // base point of the ray (k term added incrementally via fma)
    const float bx = gi * r00 + gj * r01;
    const float by = gi * r10 + gj * r11;
    const float bz = gi * r20 + gj * r21;

    const float half_inv = 1.0f / 128.0f;

    float acc = 0.0f;

#pragma unroll 4
    for (int k = 0; k < NN; ++k) {
        const float gk = (float)k - 128.0f;
        // rotated coords -> normalized [-1,1] -> pixel space, as in reference
        float px = fmaf(gk, r02, bx) * half_inv;
        float py = fmaf(gk, r12, by) * half_inv;
        float pz = fmaf(gk, r22, bz) * half_inv;
        px = fminf(fmaxf(px, -1.0f), 1.0f);
        py = fminf(fmaxf(py, -1.0f), 1.0f);
        pz = fminf(fmaxf(pz, -1.0f), 1.0f);
        px = (px + 1.0f) * 127.5f;
        py = (py + 1.0f) * 127.5f;
        pz = (pz + 1.0f) * 127.5f;

        const float fx = floorf(px), fy = floorf(py), fz = floorf(pz);
        const float tx = px - fx, ty = py - fy, tz = pz - fz;
        const int x0 = (int)fx, y0 = (int)fy, z0 = (int)fz;
        const int x1 = min(x0 + 1, NN - 1);
        const int y1 = min(y0 + 1, NN - 1);
        const int z1 = min(z0 + 1, NN - 1);

        // N=256: flat index = (z<<16) | (y<<8) | x
        const float* row00 = vol + ((z0 << 16) | (y0 << 8));
        const float* row01 = vol + ((z0 << 16) | (y1 << 8));
        const float* row10 = vol + ((z1 << 16) | (y0 << 8));
        const float* row11 = vol + ((z1 << 16) | (y1 << 8));

        const float v000 = row00[x0], v001 = row00[x1];
        const float v010 = row01[x0], v011 = row01[x1];
        const float v100 = row10[x0], v101 = row10[x1];
        const float v110 = row11[x0], v111 = row11[x1];

        const float ux = 1.0f - tx, uy = 1.0f - ty, uz = 1.0f - tz;
        const float c00 = v000 * ux + v001 * tx;
        const float c01 = v010 * ux + v011 * tx;
        const float c10 = v100 * ux + v101 * tx;
        const float c11 = v110 * ux + v111 * tx;
        const float c0 = c00 * uy + c01 * ty;
        const float c1 = c10 * uy + c11 * ty;
        acc += c0 * uz + c1 * tz;
    }

    out[(b << 16) | (i << 8) | j] = acc;
}

extern "C" void kernel_launch(void* const* d_in, const int* in_sizes, int n_in,
                              void* d_out, int out_size, void* d_ws, size_t ws_size,
                              hipStream_t stream) {
    const float* vol = (const float*)d_in[0];
    const float* quats = (const float*)d_in[1];
    float* out = (float*)d_out;

    const int B = in_sizes[1] / 4;  // quaternions: (B,4)

    dim3 grid(NN / 16, NN / 16, B);
    dim3 block(16, 16, 1);
    hipLaunchKernelGGL(rotproj_kernel, grid, block, 0, stream, vol, quats, out);
}

// Round 2
// 719.901 us; speedup vs baseline: 1.0724x; 1.0724x over previous
//
#include <hip/hip_runtime.h>

// Volume rotate + trilinear resample + projection along axis 2.
// Block = (8,8,4): each wave (tz = const) owns an 8x8 output-pixel patch and
// a 64-step k-segment of the ray p(k) = gi*R[:,0] + gj*R[:,1] + gk*R[:,2].
// Partials are LDS-reduced across the 4 waves -> one write per pixel.

#define NN 256

__global__ __launch_bounds__(256) void rotproj_kernel(
    const float* __restrict__ vol,
    const float* __restrict__ quats,
    float* __restrict__ out)
{
    const int tx = threadIdx.x;   // 0..7  -> j
    const int ty = threadIdx.y;   // 0..7  -> i
    const int tz = threadIdx.z;   // 0..3  -> k segment
    const int b = blockIdx.z;
    const int i = blockIdx.y * 8 + ty;
    const int j = blockIdx.x * 8 + tx;

    // --- quaternion -> rotation matrix (match reference numerics) ---
    const float q0 = quats[b * 4 + 0];
    const float q1 = quats[b * 4 + 1];
    const float q2 = quats[b * 4 + 2];
    const float q3 = quats[b * 4 + 3];
    const float nrm = sqrtf(q0 * q0 + q1 * q1 + q2 * q2 + q3 * q3);
    const float qw = q0 / nrm, qx = q1 / nrm, qy = q2 / nrm, qz = q3 / nrm;

    const float r00 = 1.0f - 2.0f * (qy * qy + qz * qz);
    const float r01 = 2.0f * (qx * qy - qz * qw);
    const float r02 = 2.0f * (qx * qz + qy * qw);
    const float r10 = 2.0f * (qx * qy + qz * qw);
    const float r11 = 1.0f - 2.0f * (qx * qx + qz * qz);
    const float r12 = 2.0f * (qy * qz - qx * qw);
    const float r20 = 2.0f * (qx * qz - qy * qw);
    const float r21 = 2.0f * (qy * qz + qx * qw);
    const float r22 = 1.0f - 2.0f * (qx * qx + qy * qy);

    const float gi = (float)i - 128.0f;
    const float gj = (float)j - 128.0f;

    // base point of the ray (k term added per-step via fma from the base,
    // NOT incrementally, to match reference rounding)
    const float bx = gi * r00 + gj * r01;
    const float by = gi * r10 + gj * r11;
    const float bz = gi * r20 + gj * r21;

    const float half_inv = 1.0f / 128.0f;

    float acc = 0.0f;

    const int k0 = tz * 64;
#pragma unroll 4
    for (int kk = 0; kk < 64; ++kk) {
        const int k = k0 + kk;
        const float gk = (float)k - 128.0f;
        float px = fmaf(gk, r02, bx) * half_inv;
        float py = fmaf(gk, r12, by) * half_inv;
        float pz = fmaf(gk, r22, bz) * half_inv;
        px = fminf(fmaxf(px, -1.0f), 1.0f);
        py = fminf(fmaxf(py, -1.0f), 1.0f);
        pz = fminf(fmaxf(pz, -1.0f), 1.0f);
        px = (px + 1.0f) * 127.5f;
        py = (py + 1.0f) * 127.5f;
        pz = (pz + 1.0f) * 127.5f;

        const float fx = floorf(px), fy = floorf(py), fz = floorf(pz);
        const float tfx = px - fx, tfy = py - fy, tfz = pz - fz;
        const int x0 = (int)fx, y0 = (int)fy, z0 = (int)fz;
        const int x1 = min(x0 + 1, NN - 1);
        const int y1 = min(y0 + 1, NN - 1);
        const int z1 = min(z0 + 1, NN - 1);

        // N=256: flat index = (z<<16) | (y<<8) | x
        const float* row00 = vol + ((z0 << 16) | (y0 << 8));
        const float* row01 = vol + ((z0 << 16) | (y1 << 8));
        const float* row10 = vol + ((z1 << 16) | (y0 << 8));
        const float* row11 = vol + ((z1 << 16) | (y1 << 8));

        const float v000 = row00[x0], v001 = row00[x1];
        const float v010 = row01[x0], v011 = row01[x1];
        const float v100 = row10[x0], v101 = row10[x1];
        const float v110 = row11[x0], v111 = row11[x1];

        const float ux = 1.0f - tfx, uy = 1.0f - tfy, uz = 1.0f - tfz;
        const float c00 = v000 * ux + v001 * tfx;
        const float c01 = v010 * ux + v011 * tfx;
        const float c10 = v100 * ux + v101 * tfx;
        const float c11 = v110 * ux + v111 * tfx;
        const float c0 = c00 * uy + c01 * tfy;
        const float c1 = c10 * uy + c11 * tfy;
        acc += c0 * uz + c1 * tfz;
    }

    // ---- reduce the 4 k-segment partials across waves ----
    __shared__ float sm[4][8][8];
    sm[tz][ty][tx] = acc;
    __syncthreads();
    if (tz == 0) {
        const float s = sm[0][ty][tx] + sm[1][ty][tx] +
                        sm[2][ty][tx] + sm[3][ty][tx];
        out[(b << 16) | (i << 8) | j] = s;
    }
}

extern "C" void kernel_launch(void* const* d_in, const int* in_sizes, int n_in,
                              void* d_out, int out_size, void* d_ws, size_t ws_size,
                              hipStream_t stream) {
    const float* vol = (const float*)d_in[0];
    const float* quats = (const float*)d_in[1];
    float* out = (float*)d_out;

    const int B = in_sizes[1] / 4;  // quaternions: (B,4)

    dim3 grid(NN / 8, NN / 8, B);
    dim3 block(8, 8, 4);
    hipLaunchKernelGGL(rotproj_kernel, grid, block, 0, stream, vol, quats, out);
}

// Round 3
// 473.117 us; speedup vs baseline: 1.6317x; 1.5216x over previous
//
#include <hip/hip_runtime.h>

// Volume rotate + trilinear resample + projection along axis 2.
// Gather-pipe optimization: pre-pack corner pairs so each trilinear sample
// needs 2 float4 gathers (or 4 float2, or 8 float as fallback) instead of 8.
// Pack lives in d_ws and is rebuilt every launch (harness re-poisons ws).

#define NN 256

// ---------------- pack kernels ----------------

__global__ __launch_bounds__(256) void pack4_kernel(
    const float* __restrict__ vol, float4* __restrict__ v4)
{
    const int t = blockIdx.x * 256 + threadIdx.x;   // [0, 2^24)
    const int x = t & 255;
    const int y = (t >> 8) & 255;
    const int z = t >> 16;
    const int x1 = min(x + 1, NN - 1);
    const int y1 = min(y + 1, NN - 1);
    const float* rz = vol + (z << 16);
    float4 r;
    r.x = rz[(y  << 8) | x ];   // v(z, y , x )
    r.y = rz[(y  << 8) | x1];   // v(z, y , x1)
    r.z = rz[(y1 << 8) | x ];   // v(z, y1, x )
    r.w = rz[(y1 << 8) | x1];   // v(z, y1, x1)
    v4[t] = r;
}

__global__ __launch_bounds__(256) void pack2_kernel(
    const float* __restrict__ vol, float2* __restrict__ v2)
{
    const int t = blockIdx.x * 256 + threadIdx.x;
    const int x = t & 255;
    const int x1 = min(x + 1, NN - 1);
    const int rest = t & ~255;
    float2 r;
    r.x = vol[rest | x ];
    r.y = vol[rest | x1];
    v2[t] = r;
}

// ---------------- shared geometry helper (macro-free inline) ----------------

struct RayCtx {
    float bx, by, bz;       // base point of ray (k=0 contribution excluded)
    float r02, r12, r22;    // k direction
};

__device__ __forceinline__ RayCtx make_ray(const float* __restrict__ quats,
                                           int b, int i, int j)
{
    const float q0 = quats[b * 4 + 0];
    const float q1 = quats[b * 4 + 1];
    const float q2 = quats[b * 4 + 2];
    const float q3 = quats[b * 4 + 3];
    const float nrm = sqrtf(q0 * q0 + q1 * q1 + q2 * q2 + q3 * q3);
    const float qw = q0 / nrm, qx = q1 / nrm, qy = q2 / nrm, qz = q3 / nrm;

    const float r00 = 1.0f - 2.0f * (qy * qy + qz * qz);
    const float r01 = 2.0f * (qx * qy - qz * qw);
    const float r02 = 2.0f * (qx * qz + qy * qw);
    const float r10 = 2.0f * (qx * qy + qz * qw);
    const float r11 = 1.0f - 2.0f * (qx * qx + qz * qz);
    const float r12 = 2.0f * (qy * qz - qx * qw);
    const float r20 = 2.0f * (qx * qz - qy * qw);
    const float r21 = 2.0f * (qy * qz + qx * qw);
    const float r22 = 1.0f - 2.0f * (qx * qx + qy * qy);

    const float gi = (float)i - 128.0f;
    const float gj = (float)j - 128.0f;

    RayCtx c;
    c.bx = gi * r00 + gj * r01;
    c.by = gi * r10 + gj * r11;
    c.bz = gi * r20 + gj * r21;
    c.r02 = r02; c.r12 = r12; c.r22 = r22;
    return c;
}

// Compute sample coords for step k. Returns voxel indices + fractions.
__device__ __forceinline__ void sample_coords(
    const RayCtx& c, int k,
    int& x0, int& y0, int& z0, int& z1,
    float& tfx, float& tfy, float& tfz)
{
    const float half_inv = 1.0f / 128.0f;
    const float gk = (float)k - 128.0f;
    float px = fmaf(gk, c.r02, c.bx) * half_inv;
    float py = fmaf(gk, c.r12, c.by) * half_inv;
    float pz = fmaf(gk, c.r22, c.bz) * half_inv;
    px = fminf(fmaxf(px, -1.0f), 1.0f);
    py = fminf(fmaxf(py, -1.0f), 1.0f);
    pz = fminf(fmaxf(pz, -1.0f), 1.0f);
    px = (px + 1.0f) * 127.5f;
    py = (py + 1.0f) * 127.5f;
    pz = (pz + 1.0f) * 127.5f;

    const float fx = floorf(px), fy = floorf(py), fz = floorf(pz);
    tfx = px - fx; tfy = py - fy; tfz = pz - fz;
    x0 = (int)fx; y0 = (int)fy; z0 = (int)fz;
    z1 = min(z0 + 1, NN - 1);
}

// ---------------- main kernels ----------------

// float4-packed: 2 gathers per sample.
__global__ __launch_bounds__(256) void rotproj4_kernel(
    const float4* __restrict__ v4,
    const float* __restrict__ quats,
    float* __restrict__ out)
{
    const int tx = threadIdx.x, ty = threadIdx.y, tz = threadIdx.z;
    const int b = blockIdx.z;
    const int i = blockIdx.y * 8 + ty;
    const int j = blockIdx.x * 8 + tx;

    const RayCtx c = make_ray(quats, b, i, j);

    float acc = 0.0f;
    const int k0 = tz * 64;
#pragma unroll 4
    for (int kk = 0; kk < 64; ++kk) {
        int x0, y0, z0, z1; float tfx, tfy, tfz;
        sample_coords(c, k0 + kk, x0, y0, z0, z1, tfx, tfy, tfz);

        const float4 a = v4[(z0 << 16) | (y0 << 8) | x0];
        const float4 d = v4[(z1 << 16) | (y0 << 8) | x0];

        const float ux = 1.0f - tfx, uy = 1.0f - tfy, uz = 1.0f - tfz;
        const float c00 = a.x * ux + a.y * tfx;
        const float c01 = a.z * ux + a.w * tfx;
        const float c10 = d.x * ux + d.y * tfx;
        const float c11 = d.z * ux + d.w * tfx;
        const float c0 = c00 * uy + c01 * tfy;
        const float c1 = c10 * uy + c11 * tfy;
        acc += c0 * uz + c1 * tfz;
    }

    __shared__ float sm[4][8][8];
    sm[tz][ty][tx] = acc;
    __syncthreads();
    if (tz == 0) {
        out[(b << 16) | (i << 8) | j] =
            sm[0][ty][tx] + sm[1][ty][tx] + sm[2][ty][tx] + sm[3][ty][tx];
    }
}

// float2-packed: 4 gathers per sample.
__global__ __launch_bounds__(256) void rotproj2_kernel(
    const float2* __restrict__ v2,
    const float* __restrict__ quats,
    float* __restrict__ out)
{
    const int tx = threadIdx.x, ty = threadIdx.y, tz = threadIdx.z;
    const int b = blockIdx.z;
    const int i = blockIdx.y * 8 + ty;
    const int j = blockIdx.x * 8 + tx;

    const RayCtx c = make_ray(quats, b, i, j);

    float acc = 0.0f;
    const int k0 = tz * 64;
#pragma unroll 4
    for (int kk = 0; kk < 64; ++kk) {
        int x0, y0, z0, z1; float tfx, tfy, tfz;
        sample_coords(c, k0 + kk, x0, y0, z0, z1, tfx, tfy, tfz);
        const int y1 = min(y0 + 1, NN - 1);

        const float2 a0 = v2[(z0 << 16) | (y0 << 8) | x0];
        const float2 a1 = v2[(z0 << 16) | (y1 << 8) | x0];
        const float2 d0 = v2[(z1 << 16) | (y0 << 8) | x0];
        const float2 d1 = v2[(z1 << 16) | (y1 << 8) | x0];

        const float ux = 1.0f - tfx, uy = 1.0f - tfy, uz = 1.0f - tfz;
        const float c00 = a0.x * ux + a0.y * tfx;
        const float c01 = a1.x * ux + a1.y * tfx;
        const float c10 = d0.x * ux + d0.y * tfx;
        const float c11 = d1.x * ux + d1.y * tfx;
        const float c0 = c00 * uy + c01 * tfy;
        const float c1 = c10 * uy + c11 * tfy;
        acc += c0 * uz + c1 * tfz;
    }

    __shared__ float sm[4][8][8];
    sm[tz][ty][tx] = acc;
    __syncthreads();
    if (tz == 0) {
        out[(b << 16) | (i << 8) | j] =
            sm[0][ty][tx] + sm[1][ty][tx] + sm[2][ty][tx] + sm[3][ty][tx];
    }
}

// direct (no packing) fallback — identical to the round-2 passing kernel.
__global__ __launch_bounds__(256) void rotproj_direct_kernel(
    const float* __restrict__ vol,
    const float* __restrict__ quats,
    float* __restrict__ out)
{
    const int tx = threadIdx.x, ty = threadIdx.y, tz = threadIdx.z;
    const int b = blockIdx.z;
    const int i = blockIdx.y * 8 + ty;
    const int j = blockIdx.x * 8 + tx;

    const RayCtx c = make_ray(quats, b, i, j);

    float acc = 0.0f;
    const int k0 = tz * 64;
#pragma unroll 4
    for (int kk = 0; kk < 64; ++kk) {
        int x0, y0, z0, z1; float tfx, tfy, tfz;
        sample_coords(c, k0 + kk, x0, y0, z0, z1, tfx, tfy, tfz);
        const int x1 = min(x0 + 1, NN - 1);
        const int y1 = min(y0 + 1, NN - 1);

        const float* row00 = vol + ((z0 << 16) | (y0 << 8));
        const float* row01 = vol + ((z0 << 16) | (y1 << 8));
        const float* row10 = vol + ((z1 << 16) | (y0 << 8));
        const float* row11 = vol + ((z1 << 16) | (y1 << 8));

        const float v000 = row00[x0], v001 = row00[x1];
        const float v010 = row01[x0], v011 = row01[x1];
        const float v100 = row10[x0], v101 = row10[x1];
        const float v110 = row11[x0], v111 = row11[x1];

        const float ux = 1.0f - tfx, uy = 1.0f - tfy, uz = 1.0f - tfz;
        const float c00 = v000 * ux + v001 * tfx;
        const float c01 = v010 * ux + v011 * tfx;
        const float c10 = v100 * ux + v101 * tfx;
        const float c11 = v110 * ux + v111 * tfx;
        const float c0 = c00 * uy + c01 * tfy;
        const float c1 = c10 * uy + c11 * tfy;
        acc += c0 * uz + c1 * tfz;
    }

    __shared__ float sm[4][8][8];
    sm[tz][ty][tx] = acc;
    __syncthreads();
    if (tz == 0) {
        out[(b << 16) | (i << 8) | j] =
            sm[0][ty][tx] + sm[1][ty][tx] + sm[2][ty][tx] + sm[3][ty][tx];
    }
}

// ---------------- launch ----------------

extern "C" void kernel_launch(void* const* d_in, const int* in_sizes, int n_in,
                              void* d_out, int out_size, void* d_ws, size_t ws_size,
                              hipStream_t stream) {
    const float* vol = (const float*)d_in[0];
    const float* quats = (const float*)d_in[1];
    float* out = (float*)d_out;

    const int B = in_sizes[1] / 4;  // quaternions: (B,4)
    const size_t nvox = (size_t)NN * NN * NN;
    const size_t need4 = nvox * sizeof(float4);   // 256 MiB
    const size_t need2 = nvox * sizeof(float2);   // 128 MiB

    dim3 grid(NN / 8, NN / 8, B);
    dim3 block(8, 8, 4);
    const int pack_blocks = (int)(nvox / 256);

    if (ws_size >= need4) {
        float4* v4 = (float4*)d_ws;
        hipLaunchKernelGGL(pack4_kernel, dim3(pack_blocks), dim3(256), 0, stream,
                           vol, v4);
        hipLaunchKernelGGL(rotproj4_kernel, grid, block, 0, stream, v4, quats, out);
    } else if (ws_size >= need2) {
        float2* v2 = (float2*)d_ws;
        hipLaunchKernelGGL(pack2_kernel, dim3(pack_blocks), dim3(256), 0, stream,
                           vol, v2);
        hipLaunchKernelGGL(rotproj2_kernel, grid, block, 0, stream, v2, quats, out);
    } else {
        hipLaunchKernelGGL(rotproj_direct_kernel, grid, block, 0, stream,
                           vol, quats, out);
    }
}